// Round 15
// baseline (240.465 us; speedup 1.0000x reference)
//
#include <hip/hip_runtime.h>
#include <hip/hip_bf16.h>

#define F_NODE 128
#define BINCAP 64
#define ENCB 768

typedef float f32x4 __attribute__((ext_vector_type(4)));
typedef float f32x2 __attribute__((ext_vector_type(2)));

__device__ __forceinline__ float bflo(unsigned int v) {
    return __uint_as_float(v << 16);
}
__device__ __forceinline__ float bfhi(unsigned int v) {
    return __uint_as_float(v & 0xffff0000u);
}
__device__ __forceinline__ unsigned bfpack(float f) {
    __hip_bfloat16 b = __float2bfloat16(f);
    return (unsigned)*reinterpret_cast<unsigned short*>(&b);
}

// ---------------------------------------------------------------------------
// K0: zero cursor (all blocks) + fold weights (block 0).
//  Wnp[k2][f] = pack2bf16(Wn[2k2][f], Wn[2k2+1][f])   (64x32 uints)
//  M2[k][g]  = Wg_sel @ Wl_top  (32x64; g<32 -> z)
//  cvec[g]   = bg@Wl_top + bl;  Wet[f][k] = We^T
__global__ void k_prep(const float* __restrict__ Wn,
                       const float* __restrict__ Wgz, const float* __restrict__ Wgh,
                       const float* __restrict__ Wlz, const float* __restrict__ Wlh,
                       const float* __restrict__ bgz, const float* __restrict__ bgh,
                       const float* __restrict__ blz, const float* __restrict__ blh,
                       const float* __restrict__ We,
                       unsigned* __restrict__ Wnp, float* __restrict__ M2,
                       float* __restrict__ cvec, float* __restrict__ Wet,
                       int* __restrict__ cursor, int N) {
    int tid = threadIdx.x;
    int t = blockIdx.x * 256 + tid;
    int gstride = gridDim.x * 256;
    for (int j = t; j < N; j += gstride) cursor[j] = 0;

    if (blockIdx.x != 0) return;
    for (int j = tid; j < 64 * 32; j += 256) {
        int k2 = j >> 5, f = j & 31;
        unsigned lo = bfpack(Wn[(2 * k2) * 32 + f]);
        unsigned hi = bfpack(Wn[(2 * k2 + 1) * 32 + f]);
        Wnp[j] = lo | (hi << 16);
    }
    for (int j = tid; j < 32 * 64; j += 256) {
        int k = j >> 6, g = j & 63, f = g & 31;
        const float* G = (g < 32) ? Wgz : Wgh;
        const float* L = (g < 32) ? Wlz : Wlh;   // top-half rows 0..31 of [64,32]
        float s = 0.f;
        for (int q = 0; q < 32; ++q) s += G[k * 32 + q] * L[q * 32 + f];
        M2[j] = s;
    }
    for (int j = tid; j < 64; j += 256) {
        int f = j & 31;
        const float* L  = (j < 32) ? Wlz : Wlh;
        const float* bg = (j < 32) ? bgz : bgh;
        const float* bl = (j < 32) ? blz : blh;
        float s = bl[f];
        for (int q = 0; q < 32; ++q) s += bg[q] * L[q * 32 + f];
        cvec[j] = s;
    }
    for (int j = tid; j < 32 * 32; j += 256) {
        int f = j >> 5, k = j & 31;
        Wet[j] = We[k * 32 + f];
    }
}

// ---------------------------------------------------------------------------
// K1: FAT kernel (r13-proven configuration — 1 edge/thread MM; r14's
// 2-edge variant cut occupancy 47->38% and regressed: fatm is LATENCY-bound
// on the atomic+random-store path, so wave count is the binding resource).
//  bid < ENCB : node encoder role: 2 nodes/wave, W_node packed bf16 in LDS.
//  bid >= ENCB: fused fill+MM: atomic issued early, matmul hides it.
__global__ __launch_bounds__(256) void k_fatm(
        const int* __restrict__ row, const int* __restrict__ col,
        int* __restrict__ cursor, int* __restrict__ bin,
        const float* __restrict__ ea, const float* __restrict__ Wet,
        const float* __restrict__ be, const float* __restrict__ Wout,
        const float* __restrict__ bout, float* __restrict__ out,
        const float* __restrict__ x, const float* __restrict__ bn,
        const unsigned* __restrict__ Wnp, __hip_bfloat16* __restrict__ ysb,
        int E, int N) {
    __shared__ unsigned smem[3104];  // enc: Wnp 2048 | sx 1024 | sbn 32 ; MM: 1088
    int bid = blockIdx.x, tid = threadIdx.x;

    if (bid < ENCB) {
        // ---- node encoder role ----
        unsigned* sWnp = smem;
        float*    sx   = (float*)(smem + 2048);
        float*    sbn  = (float*)(smem + 3072);
        for (int j = tid; j < 2048; j += 256) sWnp[j] = Wnp[j];
        if (tid < 32) sbn[tid] = bn[tid];
        __syncthreads();

        int w = tid >> 6, l = tid & 63;
        int f = l & 31, h2 = l >> 5;
        float* sxw = sx + w * 256 + h2 * 128;

        int NP = (N + 1) >> 1;
        int stride = ENCB * 4;
        for (int p = bid * 4 + w; p < NP; p += stride) {
            int node = 2 * p + h2;
            int nd = node < N ? node : N - 1;
            ((f32x4*)sxw)[f] = ((const f32x4*)(x + (size_t)nd * F_NODE))[f];
            // wave-private staging: no barrier needed
            float acc = sbn[f];
            #pragma unroll 8
            for (int k2 = 0; k2 < 64; ++k2) {
                unsigned wv = sWnp[k2 * 32 + f];
                acc += sxw[2 * k2] * bflo(wv) + sxw[2 * k2 + 1] * bfhi(wv);
            }
            if (node < N)
                ysb[(size_t)node * 32 + f] = __float2bfloat16(fmaxf(acc, 0.f));
        }
        return;
    }

    // ---- fused fill + edge matmul (one edge per thread) ----
    float* sW  = (float*)smem;
    float* sb  = (float*)(smem + 1024);
    float* sw3 = (float*)(smem + 1056);
    for (int j = tid; j < 1024; j += 256) sW[j] = Wet[j];
    if (tid < 32) { sb[tid] = be[tid]; sw3[tid] = Wout[64 + tid]; }
    __syncthreads();

    int e = (bid - ENCB) * 256 + tid;
    if (e >= E) return;

    int c = col[e];
    int r = row[e];
    const f32x4* erow = (const f32x4*)(ea + (size_t)e * 32);
    f32x4 er[8];
    #pragma unroll
    for (int k = 0; k < 8; ++k) er[k] = erow[k];

    int pos = atomicAdd(&cursor[c], 1);

    float p = 0.f;
    #pragma unroll 4
    for (int f = 0; f < 32; ++f) {
        const f32x4* wf = (const f32x4*)(sW + f * 32);
        f32x4 v0 = er[0] * wf[0];
        f32x4 v1 = er[1] * wf[1];
        #pragma unroll
        for (int k = 2; k < 8; k += 2) {
            v0 += er[k] * wf[k];
            v1 += er[k + 1] * wf[k + 1];
        }
        f32x4 v = v0 + v1;
        float sfin = (v[0] + v[1]) + (v[2] + v[3]);
        p += fmaxf(sb[f] + sfin, 0.f) * sw3[f];
    }
    out[e] = p + bout[0];
    if (pos < BINCAP) bin[((size_t)c << 6) + pos] = r;
}

// ---------------------------------------------------------------------------
// K2: in-place scale  ysb[i][:] *= rsqrt(deg_i + 1)  (row = 32 bf16 = 4 uint4)
__global__ __launch_bounds__(256) void k_scale(
        uint4* __restrict__ ysb4, const int* __restrict__ cursor, int N) {
    int t = blockIdx.x * 256 + threadIdx.x;
    if (t >= N * 4) return;
    float d = rsqrtf((float)cursor[t >> 2] + 1.0f);
    uint4 v = ysb4[t];
    unsigned in[4] = {v.x, v.y, v.z, v.w};
    unsigned r[4];
    #pragma unroll
    for (int j = 0; j < 4; ++j) {
        unsigned lo = bfpack(bflo(in[j]) * d);
        unsigned hi = bfpack(bfhi(in[j]) * d);
        r[j] = lo | (hi << 16);
    }
    ysb4[t] = make_uint4(r[0], r[1], r[2], r[3]);
}

// ---------------------------------------------------------------------------
// K3: persistent wave-per-node gather. M2 staged in LDS ONCE PER BLOCK
// (8KB coalesced; r13 loaded it into registers per-WAVE = 268MB L2 setup
// traffic + 32 VGPRs -> only ~4 waves/SIMD on a latency-bound kernel).
// Epilogue matvec reads LDS: lanes hit 64 consecutive floats = 2-way bank
// aliasing (free, m136). Lane (q=l&7, s=l>>3): uint2 = 4 bf16/lane,
// 8 lanes/edge -> 8 edges in flight.
__global__ __launch_bounds__(256) void k_gather(
        const int* __restrict__ cursor, const int* __restrict__ bin,
        const unsigned short* __restrict__ ysb,
        const float* __restrict__ M2, const float* __restrict__ cvec,
        const float* __restrict__ Wout,
        float* __restrict__ hr, float* __restrict__ hc, int N) {
    __shared__ float sM[2048];
    __shared__ float scv[64], sw0[32], sw1[32];
    int tid = threadIdx.x;
    for (int j = tid; j < 2048; j += 256) sM[j] = M2[j];
    if (tid < 64) scv[tid] = cvec[tid];
    if (tid < 32) { sw0[tid] = Wout[tid]; sw1[tid] = Wout[32 + tid]; }
    __syncthreads();

    int w = tid >> 6, l = tid & 63;
    int q = l & 7, s = l >> 3;
    float cvl = scv[l];
    float w0l = sw0[l & 31];
    float w1l = sw1[l & 31];

    int stride = gridDim.x * 4;
    for (int c = blockIdx.x * 4 + w; c < N; c += stride) {
        int truec = cursor[c];
        float dc = rsqrtf((float)truec + 1.0f);
        int cnt = truec < BINCAP ? truec : BINCAP;
        const int* bp = bin + ((size_t)c << 6);
        int myr = (l < cnt) ? bp[l] : 0;

        float a0 = 0.f, a1 = 0.f, a2 = 0.f, a3 = 0.f;
        uint2 sv = *(const uint2*)(ysb + (size_t)c * 32 + 4 * q);
        if (s == 0) {
            a0 = bflo(sv.x); a1 = bfhi(sv.x);
            a2 = bflo(sv.y); a3 = bfhi(sv.y);
        }
        for (int j = 0; j < cnt; j += 8) {
            int jj = j + s;
            if (jj < cnt) {
                int r = __shfl(myr, jj);
                uint2 v = *(const uint2*)(ysb + (size_t)r * 32 + 4 * q);
                a0 += bflo(v.x); a1 += bfhi(v.x);
                a2 += bflo(v.y); a3 += bfhi(v.y);
            }
        }
        a0 += __shfl_xor(a0, 8);  a1 += __shfl_xor(a1, 8);
        a2 += __shfl_xor(a2, 8);  a3 += __shfl_xor(a3, 8);
        a0 += __shfl_xor(a0, 16); a1 += __shfl_xor(a1, 16);
        a2 += __shfl_xor(a2, 16); a3 += __shfl_xor(a3, 16);
        a0 += __shfl_xor(a0, 32); a1 += __shfl_xor(a1, 32);
        a2 += __shfl_xor(a2, 32); a3 += __shfl_xor(a3, 32);
        // lane with q=kq now holds S[4kq..4kq+3] in a0..a3

        float acc = 0.f;
        #pragma unroll
        for (int kq = 0; kq < 8; ++kq) {
            float s0 = __shfl(a0, kq), t1 = __shfl(a1, kq);
            float t2 = __shfl(a2, kq), t3 = __shfl(a3, kq);
            acc += s0 * sM[(4 * kq) * 64 + l]     + t1 * sM[(4 * kq + 1) * 64 + l]
                 + t2 * sM[(4 * kq + 2) * 64 + l] + t3 * sM[(4 * kq + 3) * 64 + l];
        }
        float a = dc * acc + cvl;
        float v = (l < 32) ? (1.f / (1.f + __expf(-a))) : tanhf(a);
        float o = __shfl_xor(v, 32);
        float h = (1.f - v) * o;             // valid on lanes l<32
        float pr = h * w0l;
        float pc = h * w1l;
        #pragma unroll
        for (int m = 16; m >= 1; m >>= 1) {
            pr += __shfl_xor(pr, m);
            pc += __shfl_xor(pc, m);
        }
        if (l == 0) { hr[c] = pr; hc[c] = pc; }
    }
}

// ---------------------------------------------------------------------------
// K4: out[e] += hr[row[e]] + hc[col[e]]   (hr/hc 400KB each: L2/L3-resident)
__global__ __launch_bounds__(256) void k_edge_add(
        const int* __restrict__ row, const int* __restrict__ col,
        const float* __restrict__ hr, const float* __restrict__ hc,
        float* __restrict__ out, int E) {
    int e = blockIdx.x * 256 + threadIdx.x;
    if (e < E) out[e] += hr[row[e]] + hc[col[e]];
}

// ---------------------------------------------------------------------------
extern "C" void kernel_launch(void* const* d_in, const int* in_sizes, int n_in,
                              void* d_out, int out_size, void* d_ws, size_t ws_size,
                              hipStream_t stream) {
    const float* x    = (const float*)d_in[0];
    const int*   ei   = (const int*)  d_in[1];
    const float* ea   = (const float*)d_in[2];
    const float* Wn   = (const float*)d_in[3];
    const float* bn   = (const float*)d_in[4];
    const float* We   = (const float*)d_in[5];
    const float* be   = (const float*)d_in[6];
    const float* Wgz  = (const float*)d_in[7];
    const float* bgz  = (const float*)d_in[8];
    // d_in[9..10] = Wg_r, bg_r : dead (h0 == 0)
    const float* Wgh  = (const float*)d_in[11];
    const float* bgh  = (const float*)d_in[12];
    const float* Wlz  = (const float*)d_in[13];
    const float* blz  = (const float*)d_in[14];
    // d_in[15..16] = Wl_r, bl_r : dead
    const float* Wlh  = (const float*)d_in[17];
    const float* blh  = (const float*)d_in[18];
    const float* Wout = (const float*)d_in[19];
    const float* bout = (const float*)d_in[20];

    int N = in_sizes[0] / F_NODE;
    int E = in_sizes[1] / 2;
    const int* row = ei;
    const int* col = ei + E;

    // ws layout (float units):
    // ysb(bf16)[32N]=16N | bin(int)[64N] | Wnp(uint)[2048] | M2[2048]
    // | Wet[1024] | cvec[64] | hr[N] | hc[N] | cursor(int)[N]
    float* ws    = (float*)d_ws;
    __hip_bfloat16* ysb = (__hip_bfloat16*)ws;
    int*   bin   = (int*)(ws + (size_t)16 * N);
    unsigned* Wnp= (unsigned*)(ws + (size_t)80 * N);
    float* M2    = ws + (size_t)80 * N + 2048;
    float* Wet   = M2 + 2048;
    float* cvec  = Wet + 1024;
    float* hr    = cvec + 64;
    float* hc    = hr + N;
    int*   cursor= (int*)(hc + N);
    float* out   = (float*)d_out;

    k_prep<<<400, 256, 0, stream>>>(Wn, Wgz, Wgh, Wlz, Wlh, bgz, bgh, blz, blh,
                                    We, Wnp, M2, cvec, Wet, cursor, N);
    int eb = (E + 255) / 256;
    k_fatm<<<ENCB + eb, 256, 0, stream>>>(row, col, cursor, bin, ea, Wet, be,
                                          Wout, bout, out, x, bn, Wnp, ysb,
                                          E, N);
    k_scale<<<(4 * N + 255) / 256, 256, 0, stream>>>((uint4*)ysb, cursor, N);
    k_gather<<<8192, 256, 0, stream>>>(cursor, bin, (const unsigned short*)ysb,
                                       M2, cvec, Wout, hr, hc, N);
    k_edge_add<<<eb, 256, 0, stream>>>(row, col, hr, hc, out, E);
}

// Round 16
// 228.339 us; speedup vs baseline: 1.0531x; 1.0531x over previous
//
#include <hip/hip_runtime.h>
#include <hip/hip_bf16.h>

#define F_NODE 128
#define BINCAP 64
#define ENCB 768

typedef float f32x4 __attribute__((ext_vector_type(4)));
typedef float f32x2 __attribute__((ext_vector_type(2)));

__device__ __forceinline__ float bflo(unsigned int v) {
    return __uint_as_float(v << 16);
}
__device__ __forceinline__ float bfhi(unsigned int v) {
    return __uint_as_float(v & 0xffff0000u);
}
__device__ __forceinline__ unsigned bfpack(float f) {
    __hip_bfloat16 b = __float2bfloat16(f);
    return (unsigned)*reinterpret_cast<unsigned short*>(&b);
}

// ---------------------------------------------------------------------------
// K0: zero cursor (all blocks) + fold weights (block 0).
//  Wnp[k2][f] = pack2bf16(Wn[2k2][f], Wn[2k2+1][f])   (64x32 uints)
//  M2[k][g]  = Wg_sel @ Wl_top  (32x64; g<32 -> z)
//  cvec[g]   = bg@Wl_top + bl;  Wet[f][k] = We^T
__global__ void k_prep(const float* __restrict__ Wn,
                       const float* __restrict__ Wgz, const float* __restrict__ Wgh,
                       const float* __restrict__ Wlz, const float* __restrict__ Wlh,
                       const float* __restrict__ bgz, const float* __restrict__ bgh,
                       const float* __restrict__ blz, const float* __restrict__ blh,
                       const float* __restrict__ We,
                       unsigned* __restrict__ Wnp, float* __restrict__ M2,
                       float* __restrict__ cvec, float* __restrict__ Wet,
                       int* __restrict__ cursor, int N) {
    int tid = threadIdx.x;
    int t = blockIdx.x * 256 + tid;
    int gstride = gridDim.x * 256;
    for (int j = t; j < N; j += gstride) cursor[j] = 0;

    if (blockIdx.x != 0) return;
    for (int j = tid; j < 64 * 32; j += 256) {
        int k2 = j >> 5, f = j & 31;
        unsigned lo = bfpack(Wn[(2 * k2) * 32 + f]);
        unsigned hi = bfpack(Wn[(2 * k2 + 1) * 32 + f]);
        Wnp[j] = lo | (hi << 16);
    }
    for (int j = tid; j < 32 * 64; j += 256) {
        int k = j >> 6, g = j & 63, f = g & 31;
        const float* G = (g < 32) ? Wgz : Wgh;
        const float* L = (g < 32) ? Wlz : Wlh;   // top-half rows 0..31 of [64,32]
        float s = 0.f;
        for (int q = 0; q < 32; ++q) s += G[k * 32 + q] * L[q * 32 + f];
        M2[j] = s;
    }
    for (int j = tid; j < 64; j += 256) {
        int f = j & 31;
        const float* L  = (j < 32) ? Wlz : Wlh;
        const float* bg = (j < 32) ? bgz : bgh;
        const float* bl = (j < 32) ? blz : blh;
        float s = bl[f];
        for (int q = 0; q < 32; ++q) s += bg[q] * L[q * 32 + f];
        cvec[j] = s;
    }
    for (int j = tid; j < 32 * 32; j += 256) {
        int f = j >> 5, k = j & 31;
        Wet[j] = We[k * 32 + f];
    }
}

// ---------------------------------------------------------------------------
// K1: FAT kernel (r13-proven; fatm is at the random-64B-line HBM ceiling —
// hbm_bytes/dur = 1.79 TB/s, the effective max for scattered granules).
//  bid < ENCB : node encoder role: 2 nodes/wave, W_node packed bf16 in LDS.
//  bid >= ENCB: fused fill+MM, 1 edge/thread: atomic early, matmul hides it.
__global__ __launch_bounds__(256) void k_fatm(
        const int* __restrict__ row, const int* __restrict__ col,
        int* __restrict__ cursor, int* __restrict__ bin,
        const float* __restrict__ ea, const float* __restrict__ Wet,
        const float* __restrict__ be, const float* __restrict__ Wout,
        const float* __restrict__ bout, float* __restrict__ out,
        const float* __restrict__ x, const float* __restrict__ bn,
        const unsigned* __restrict__ Wnp, __hip_bfloat16* __restrict__ ysb,
        int E, int N) {
    __shared__ unsigned smem[3104];  // enc: Wnp 2048 | sx 1024 | sbn 32 ; MM: 1088
    int bid = blockIdx.x, tid = threadIdx.x;

    if (bid < ENCB) {
        // ---- node encoder role ----
        unsigned* sWnp = smem;
        float*    sx   = (float*)(smem + 2048);
        float*    sbn  = (float*)(smem + 3072);
        for (int j = tid; j < 2048; j += 256) sWnp[j] = Wnp[j];
        if (tid < 32) sbn[tid] = bn[tid];
        __syncthreads();

        int w = tid >> 6, l = tid & 63;
        int f = l & 31, h2 = l >> 5;
        float* sxw = sx + w * 256 + h2 * 128;

        int NP = (N + 1) >> 1;
        int stride = ENCB * 4;
        for (int p = bid * 4 + w; p < NP; p += stride) {
            int node = 2 * p + h2;
            int nd = node < N ? node : N - 1;
            ((f32x4*)sxw)[f] = ((const f32x4*)(x + (size_t)nd * F_NODE))[f];
            // wave-private staging: no barrier needed
            float acc = sbn[f];
            #pragma unroll 8
            for (int k2 = 0; k2 < 64; ++k2) {
                unsigned wv = sWnp[k2 * 32 + f];
                acc += sxw[2 * k2] * bflo(wv) + sxw[2 * k2 + 1] * bfhi(wv);
            }
            if (node < N)
                ysb[(size_t)node * 32 + f] = __float2bfloat16(fmaxf(acc, 0.f));
        }
        return;
    }

    // ---- fused fill + edge matmul (one edge per thread) ----
    float* sW  = (float*)smem;
    float* sb  = (float*)(smem + 1024);
    float* sw3 = (float*)(smem + 1056);
    for (int j = tid; j < 1024; j += 256) sW[j] = Wet[j];
    if (tid < 32) { sb[tid] = be[tid]; sw3[tid] = Wout[64 + tid]; }
    __syncthreads();

    int e = (bid - ENCB) * 256 + tid;
    if (e >= E) return;

    int c = col[e];
    int r = row[e];
    const f32x4* erow = (const f32x4*)(ea + (size_t)e * 32);
    f32x4 er[8];
    #pragma unroll
    for (int k = 0; k < 8; ++k) er[k] = erow[k];

    int pos = atomicAdd(&cursor[c], 1);

    float p = 0.f;
    #pragma unroll 4
    for (int f = 0; f < 32; ++f) {
        const f32x4* wf = (const f32x4*)(sW + f * 32);
        f32x4 v0 = er[0] * wf[0];
        f32x4 v1 = er[1] * wf[1];
        #pragma unroll
        for (int k = 2; k < 8; k += 2) {
            v0 += er[k] * wf[k];
            v1 += er[k + 1] * wf[k + 1];
        }
        f32x4 v = v0 + v1;
        float sfin = (v[0] + v[1]) + (v[2] + v[3]);
        p += fmaxf(sb[f] + sfin, 0.f) * sw3[f];
    }
    out[e] = p + bout[0];
    if (pos < BINCAP) bin[((size_t)c << 6) + pos] = r;
}

// ---------------------------------------------------------------------------
// K2: in-place scale  ysb[i][:] *= rsqrt(deg_i + 1)  (row = 32 bf16 = 4 uint4)
__global__ __launch_bounds__(256) void k_scale(
        uint4* __restrict__ ysb4, const int* __restrict__ cursor, int N) {
    int t = blockIdx.x * 256 + threadIdx.x;
    if (t >= N * 4) return;
    float d = rsqrtf((float)cursor[t >> 2] + 1.0f);
    uint4 v = ysb4[t];
    unsigned in[4] = {v.x, v.y, v.z, v.w};
    unsigned r[4];
    #pragma unroll
    for (int j = 0; j < 4; ++j) {
        unsigned lo = bfpack(bflo(in[j]) * d);
        unsigned hi = bfpack(bfhi(in[j]) * d);
        r[j] = lo | (hi << 16);
    }
    ysb4[t] = make_uint4(r[0], r[1], r[2], r[3]);
}

// ---------------------------------------------------------------------------
// K3: persistent wave-per-node gather, r13 register-mcol form (LDS variant
// was 9us slower, r15) + SOFTWARE PIPELINE: next node's cursor, bin row and
// self ysb row are prefetched during the current node's compute (~200 VALU
// ops cover the ~500cy random-load latency). Bin row loaded unconditionally
// (garbage beyond cnt never consumed via shfl guard).
__global__ __launch_bounds__(256) void k_gather(
        const int* __restrict__ cursor, const int* __restrict__ bin,
        const unsigned short* __restrict__ ysb,
        const float* __restrict__ M2, const float* __restrict__ cvec,
        const float* __restrict__ Wout,
        float* __restrict__ hr, float* __restrict__ hc, int N) {
    int tid = threadIdx.x;
    int w = tid >> 6, l = tid & 63;
    int q = l & 7, s = l >> 3;

    float mcol[32];
    #pragma unroll
    for (int k = 0; k < 32; ++k) mcol[k] = M2[k * 64 + l];
    float cvl = cvec[l];
    float w0l = Wout[l & 31];
    float w1l = Wout[32 + (l & 31)];

    int stride = gridDim.x * 4;
    int c = blockIdx.x * 4 + w;
    if (c >= N) return;

    // preload first node
    int truec = cursor[c];
    int myr = bin[((size_t)c << 6) + l];
    uint2 sv = *(const uint2*)(ysb + (size_t)c * 32 + 4 * q);

    while (true) {
        // ---- prefetch next node ----
        int cN = c + stride;
        int truecN = 0, myrN = 0;
        uint2 svN = make_uint2(0u, 0u);
        if (cN < N) {
            truecN = cursor[cN];
            myrN   = bin[((size_t)cN << 6) + l];
            svN    = *(const uint2*)(ysb + (size_t)cN * 32 + 4 * q);
        }

        // ---- process current node ----
        float dc = rsqrtf((float)truec + 1.0f);
        int cnt = truec < BINCAP ? truec : BINCAP;

        float a0 = 0.f, a1 = 0.f, a2 = 0.f, a3 = 0.f;
        if (s == 0) {
            a0 = bflo(sv.x); a1 = bfhi(sv.x);
            a2 = bflo(sv.y); a3 = bfhi(sv.y);
        }
        for (int j = 0; j < cnt; j += 8) {
            int jj = j + s;
            if (jj < cnt) {
                int r = __shfl(myr, jj);
                uint2 v = *(const uint2*)(ysb + (size_t)r * 32 + 4 * q);
                a0 += bflo(v.x); a1 += bfhi(v.x);
                a2 += bflo(v.y); a3 += bfhi(v.y);
            }
        }
        a0 += __shfl_xor(a0, 8);  a1 += __shfl_xor(a1, 8);
        a2 += __shfl_xor(a2, 8);  a3 += __shfl_xor(a3, 8);
        a0 += __shfl_xor(a0, 16); a1 += __shfl_xor(a1, 16);
        a2 += __shfl_xor(a2, 16); a3 += __shfl_xor(a3, 16);
        a0 += __shfl_xor(a0, 32); a1 += __shfl_xor(a1, 32);
        a2 += __shfl_xor(a2, 32); a3 += __shfl_xor(a3, 32);
        // lane with q=kq now holds S[4kq..4kq+3] in a0..a3

        float acc = 0.f;
        #pragma unroll
        for (int kq = 0; kq < 8; ++kq) {
            float s0 = __shfl(a0, kq), t1 = __shfl(a1, kq);
            float t2 = __shfl(a2, kq), t3 = __shfl(a3, kq);
            acc += s0 * mcol[4 * kq]     + t1 * mcol[4 * kq + 1]
                 + t2 * mcol[4 * kq + 2] + t3 * mcol[4 * kq + 3];
        }
        float a = dc * acc + cvl;
        float v = (l < 32) ? (1.f / (1.f + __expf(-a))) : tanhf(a);
        float o = __shfl_xor(v, 32);
        float h = (1.f - v) * o;             // valid on lanes l<32
        float pr = h * w0l;
        float pc = h * w1l;
        #pragma unroll
        for (int m = 16; m >= 1; m >>= 1) {
            pr += __shfl_xor(pr, m);
            pc += __shfl_xor(pc, m);
        }
        if (l == 0) { hr[c] = pr; hc[c] = pc; }

        if (cN >= N) break;
        c = cN; truec = truecN; myr = myrN; sv = svN;
    }
}

// ---------------------------------------------------------------------------
// K4: out[e] += hr[row[e]] + hc[col[e]]   (hr/hc 400KB each: L2/L3-resident)
__global__ __launch_bounds__(256) void k_edge_add(
        const int* __restrict__ row, const int* __restrict__ col,
        const float* __restrict__ hr, const float* __restrict__ hc,
        float* __restrict__ out, int E) {
    int e = blockIdx.x * 256 + threadIdx.x;
    if (e < E) out[e] += hr[row[e]] + hc[col[e]];
}

// ---------------------------------------------------------------------------
extern "C" void kernel_launch(void* const* d_in, const int* in_sizes, int n_in,
                              void* d_out, int out_size, void* d_ws, size_t ws_size,
                              hipStream_t stream) {
    const float* x    = (const float*)d_in[0];
    const int*   ei   = (const int*)  d_in[1];
    const float* ea   = (const float*)d_in[2];
    const float* Wn   = (const float*)d_in[3];
    const float* bn   = (const float*)d_in[4];
    const float* We   = (const float*)d_in[5];
    const float* be   = (const float*)d_in[6];
    const float* Wgz  = (const float*)d_in[7];
    const float* bgz  = (const float*)d_in[8];
    // d_in[9..10] = Wg_r, bg_r : dead (h0 == 0)
    const float* Wgh  = (const float*)d_in[11];
    const float* bgh  = (const float*)d_in[12];
    const float* Wlz  = (const float*)d_in[13];
    const float* blz  = (const float*)d_in[14];
    // d_in[15..16] = Wl_r, bl_r : dead
    const float* Wlh  = (const float*)d_in[17];
    const float* blh  = (const float*)d_in[18];
    const float* Wout = (const float*)d_in[19];
    const float* bout = (const float*)d_in[20];

    int N = in_sizes[0] / F_NODE;
    int E = in_sizes[1] / 2;
    const int* row = ei;
    const int* col = ei + E;

    // ws layout (float units):
    // ysb(bf16)[32N]=16N | bin(int)[64N] | Wnp(uint)[2048] | M2[2048]
    // | Wet[1024] | cvec[64] | hr[N] | hc[N] | cursor(int)[N]
    float* ws    = (float*)d_ws;
    __hip_bfloat16* ysb = (__hip_bfloat16*)ws;
    int*   bin   = (int*)(ws + (size_t)16 * N);
    unsigned* Wnp= (unsigned*)(ws + (size_t)80 * N);
    float* M2    = ws + (size_t)80 * N + 2048;
    float* Wet   = M2 + 2048;
    float* cvec  = Wet + 1024;
    float* hr    = cvec + 64;
    float* hc    = hr + N;
    int*   cursor= (int*)(hc + N);
    float* out   = (float*)d_out;

    k_prep<<<400, 256, 0, stream>>>(Wn, Wgz, Wgh, Wlz, Wlh, bgz, bgh, blz, blh,
                                    We, Wnp, M2, cvec, Wet, cursor, N);
    int eb = (E + 255) / 256;
    k_fatm<<<ENCB + eb, 256, 0, stream>>>(row, col, cursor, bin, ea, Wet, be,
                                          Wout, bout, out, x, bn, Wnp, ysb,
                                          E, N);
    k_scale<<<(4 * N + 255) / 256, 256, 0, stream>>>((uint4*)ysb, cursor, N);
    k_gather<<<8192, 256, 0, stream>>>(cursor, bin, (const unsigned short*)ysb,
                                       M2, cvec, Wout, hr, hc, N);
    k_edge_add<<<eb, 256, 0, stream>>>(row, col, hr, hc, out, E);
}